// Round 1
// baseline (695.305 us; speedup 1.0000x reference)
//
#include <hip/hip_runtime.h>
#include <cstdint>
#include <cstddef>

// ---------------- graph preprocessing ----------------

__global__ void k_zero_i32(int* __restrict__ p, int n) {
  int i = blockIdx.x * blockDim.x + threadIdx.x;
  if (i < n) p[i] = 0;
}

__global__ void k_count(const int* __restrict__ dst, int* __restrict__ count, int E) {
  int e = blockIdx.x * blockDim.x + threadIdx.x;
  if (e < E) atomicAdd(&count[dst[e]], 1);
}

__global__ void k_dinv(const int* __restrict__ count, float* __restrict__ dinv, int n) {
  int i = blockIdx.x * blockDim.x + threadIdx.x;
  if (i < n) dinv[i] = rsqrtf((float)(count[i] + 1));  // +1 self-loop
}

// inclusive scan of 1024-chunks; chunk-local inclusive into `incl`, chunk totals into bsum
__global__ void k_scan1(const int* __restrict__ count, int* __restrict__ incl,
                        int* __restrict__ bsum, int n) {
  __shared__ int tmp[1024];
  int tid = threadIdx.x;
  int gid = blockIdx.x * 1024 + tid;
  int v = (gid < n) ? count[gid] : 0;
  tmp[tid] = v;
  __syncthreads();
  for (int off = 1; off < 1024; off <<= 1) {
    int t = (tid >= off) ? tmp[tid - off] : 0;
    __syncthreads();
    tmp[tid] += t;
    __syncthreads();
  }
  if (gid < n) incl[gid] = tmp[tid];
  if (tid == 1023) bsum[blockIdx.x] = tmp[tid];
}

// exclusive scan over block sums (nb <= 1024)
__global__ void k_scan2(int* __restrict__ bsum, int nb) {
  __shared__ int tmp[1024];
  int tid = threadIdx.x;
  int v = (tid < nb) ? bsum[tid] : 0;
  tmp[tid] = v;
  __syncthreads();
  for (int off = 1; off < 1024; off <<= 1) {
    int t = (tid >= off) ? tmp[tid - off] : 0;
    __syncthreads();
    tmp[tid] += t;
    __syncthreads();
  }
  if (tid < nb) bsum[tid] = tmp[tid] - v;  // exclusive
}

// finalize: offset[i] = exclusive scan; fill[i] = offset[i]; offset[n] = E
__global__ void k_scan3(const int* __restrict__ count, int* __restrict__ offset,
                        const int* __restrict__ bsum, int* __restrict__ fill, int n, int E) {
  int gid = blockIdx.x * blockDim.x + threadIdx.x;
  if (gid < n) {
    int off = offset[gid] - count[gid] + bsum[gid >> 10];
    offset[gid] = off;
    fill[gid] = off;
  }
  if (gid == 0) offset[n] = E;
}

// counting-sort scatter: edge -> CSR slot (sorted by dst); precompute edge norm
__global__ void k_scatter(const int* __restrict__ src, const int* __restrict__ dst,
                          const float* __restrict__ dinv, int* __restrict__ fill,
                          int* __restrict__ ssrc, float* __restrict__ snorm, int E) {
  int e = blockIdx.x * blockDim.x + threadIdx.x;
  if (e < E) {
    int s = src[e], d = dst[e];
    int pos = atomicAdd(&fill[d], 1);
    ssrc[pos] = s;
    snorm[pos] = dinv[s] * dinv[d];
  }
}

// ---------------- dense layers ----------------
// One wave per node; W column `lane` lives entirely in VGPRs; x row is
// wave-uniform (readfirstlane) so loads scalarize. out[node][lane] coalesced.
template <int K, int COLS>
__global__ __launch_bounds__(256) void k_gemm(const float* __restrict__ x,
                                              const float* __restrict__ W,
                                              float* __restrict__ out, int n) {
  int lane = threadIdx.x & 63;
  int gw = (blockIdx.x * blockDim.x + threadIdx.x) >> 6;
  int nw = (gridDim.x * blockDim.x) >> 6;
  float wreg[K];
#pragma unroll
  for (int k = 0; k < K; ++k) wreg[k] = 0.f;
  if (lane < COLS) {
#pragma unroll
    for (int k = 0; k < K; ++k) wreg[k] = W[k * COLS + lane];
  }
  for (int node = gw; node < n; node += nw) {
    int un = __builtin_amdgcn_readfirstlane(node);
    const float* xr = x + (size_t)un * K;
    float acc = 0.f;
#pragma unroll
    for (int k = 0; k < K; ++k) acc = fmaf(xr[k], wreg[k], acc);
    if (lane < COLS) out[(size_t)un * COLS + lane] = acc;
  }
}

// ---------------- aggregation (CSR gather, no atomics) ----------------
// One wave per node, lane = feature. acc init = self-loop term; fused bias(+relu).
template <int F, bool RELU>
__global__ __launch_bounds__(256) void k_agg(const float* __restrict__ h,
                                             const int* __restrict__ offset,
                                             const int* __restrict__ ssrc,
                                             const float* __restrict__ snorm,
                                             const float* __restrict__ dinv,
                                             const float* __restrict__ bias,
                                             float* __restrict__ out, int n) {
  int lane = threadIdx.x & 63;
  int node = (blockIdx.x * blockDim.x + threadIdx.x) >> 6;
  if (node >= n) return;
  float di = dinv[node];
  float acc = 0.f;
  if (lane < F) acc = h[(size_t)node * F + lane] * di * di;  // self loop
  int beg = offset[node], end = offset[node + 1];
  for (int j = beg; j < end; ++j) {
    int s = ssrc[j];
    float nm = snorm[j];
    if (lane < F) acc = fmaf(h[(size_t)s * F + lane], nm, acc);
  }
  if (lane < F) {
    float v = acc + bias[lane];
    if (RELU) v = v > 0.f ? v : 0.f;
    out[(size_t)node * F + lane] = v;
  }
}

// ---------------- launch ----------------

extern "C" void kernel_launch(void* const* d_in, const int* in_sizes, int n_in,
                              void* d_out, int out_size, void* d_ws, size_t ws_size,
                              hipStream_t stream) {
  const float* x  = (const float*)d_in[0];
  const int*   ei = (const int*)d_in[1];
  const float* W1 = (const float*)d_in[2];
  const float* b1 = (const float*)d_in[3];
  const float* W2 = (const float*)d_in[4];
  const float* b2 = (const float*)d_in[5];
  float* out = (float*)d_out;

  const int F_IN = 128, HID = 64, C = 40;
  int N = in_sizes[0] / F_IN;
  int E = in_sizes[1] / 2;
  const int* src = ei;
  const int* dst = ei + E;

  char* w = (char*)d_ws;
  size_t o = 0;
  auto alloc = [&](size_t bytes) -> void* {
    void* p = w + o;
    o = (o + bytes + 255) & ~(size_t)255;
    return p;
  };
  float* dinv   = (float*)alloc((size_t)N * 4);
  int*   count  = (int*)alloc((size_t)N * 4);
  int*   offset = (int*)alloc((size_t)(N + 1) * 4);
  int*   fill   = (int*)alloc((size_t)N * 4);
  int*   bsum   = (int*)alloc(1024 * 4);
  int*   ssrc   = (int*)alloc((size_t)E * 4);
  float* snorm  = (float*)alloc((size_t)E * 4);
  float* h      = (float*)alloc((size_t)N * HID * 4);
  float* h1     = (float*)alloc((size_t)N * HID * 4);
  float* h2     = (float*)alloc((size_t)N * C * 4);

  int nb = (N + 1023) / 1024;  // 98 for N=100000

  dim3 b256(256);
  dim3 gN((N + 255) / 256), gE((E + 255) / 256);

  // degree / CSR build
  k_zero_i32<<<gN, b256, 0, stream>>>(count, N);
  k_count<<<gE, b256, 0, stream>>>(dst, count, E);
  k_dinv<<<gN, b256, 0, stream>>>(count, dinv, N);
  k_scan1<<<dim3(nb), dim3(1024), 0, stream>>>(count, offset, bsum, N);
  k_scan2<<<dim3(1), dim3(1024), 0, stream>>>(bsum, nb);
  k_scan3<<<gN, b256, 0, stream>>>(count, offset, bsum, fill, N, E);
  k_scatter<<<gE, b256, 0, stream>>>(src, dst, dinv, fill, ssrc, snorm, E);

  // layer 1
  k_gemm<128, 64><<<dim3(768), b256, 0, stream>>>(x, W1, h, N);
  k_agg<64, true><<<dim3((N + 3) / 4), b256, 0, stream>>>(h, offset, ssrc, snorm, dinv, b1, h1, N);

  // layer 2
  k_gemm<64, 40><<<dim3(768), b256, 0, stream>>>(h1, W2, h2, N);
  k_agg<40, false><<<dim3((N + 3) / 4), b256, 0, stream>>>(h2, offset, ssrc, snorm, dinv, b2, out, N);
}

// Round 2
// 512.359 us; speedup vs baseline: 1.3571x; 1.3571x over previous
//
#include <hip/hip_runtime.h>
#include <cstdint>
#include <cstddef>

// ---------------- graph preprocessing ----------------

__global__ void k_zero_i32(int* __restrict__ p, int n) {
  int i = blockIdx.x * blockDim.x + threadIdx.x;
  if (i < n) p[i] = 0;
}

__global__ void k_count(const int* __restrict__ dst, int* __restrict__ count, int E) {
  int e = blockIdx.x * blockDim.x + threadIdx.x;
  if (e < E) atomicAdd(&count[dst[e]], 1);
}

__global__ void k_dinv(const int* __restrict__ count, float* __restrict__ dinv, int n) {
  int i = blockIdx.x * blockDim.x + threadIdx.x;
  if (i < n) dinv[i] = rsqrtf((float)(count[i] + 1));  // +1 self-loop
}

// inclusive scan of 1024-chunks; chunk-local inclusive into `incl`, chunk totals into bsum
__global__ void k_scan1(const int* __restrict__ count, int* __restrict__ incl,
                        int* __restrict__ bsum, int n) {
  __shared__ int tmp[1024];
  int tid = threadIdx.x;
  int gid = blockIdx.x * 1024 + tid;
  int v = (gid < n) ? count[gid] : 0;
  tmp[tid] = v;
  __syncthreads();
  for (int off = 1; off < 1024; off <<= 1) {
    int t = (tid >= off) ? tmp[tid - off] : 0;
    __syncthreads();
    tmp[tid] += t;
    __syncthreads();
  }
  if (gid < n) incl[gid] = tmp[tid];
  if (tid == 1023) bsum[blockIdx.x] = tmp[tid];
}

// exclusive scan over block sums (nb <= 1024)
__global__ void k_scan2(int* __restrict__ bsum, int nb) {
  __shared__ int tmp[1024];
  int tid = threadIdx.x;
  int v = (tid < nb) ? bsum[tid] : 0;
  tmp[tid] = v;
  __syncthreads();
  for (int off = 1; off < 1024; off <<= 1) {
    int t = (tid >= off) ? tmp[tid - off] : 0;
    __syncthreads();
    tmp[tid] += t;
    __syncthreads();
  }
  if (tid < nb) bsum[tid] = tmp[tid] - v;  // exclusive
}

// finalize: offset[i] = exclusive scan; fill[i] = offset[i]; offset[n] = E
__global__ void k_scan3(const int* __restrict__ count, int* __restrict__ offset,
                        const int* __restrict__ bsum, int* __restrict__ fill, int n, int E) {
  int gid = blockIdx.x * blockDim.x + threadIdx.x;
  if (gid < n) {
    int off = offset[gid] - count[gid] + bsum[gid >> 10];
    offset[gid] = off;
    fill[gid] = off;
  }
  if (gid == 0) offset[n] = E;
}

// counting-sort scatter: edge -> CSR slot (sorted by dst); pack (src, norm) as int2
__global__ void k_scatter(const int* __restrict__ src, const int* __restrict__ dst,
                          const float* __restrict__ dinv, int* __restrict__ fill,
                          int2* __restrict__ sedge, int E) {
  int e = blockIdx.x * blockDim.x + threadIdx.x;
  if (e < E) {
    int s = src[e], d = dst[e];
    int pos = atomicAdd(&fill[d], 1);
    float nm = dinv[s] * dinv[d];
    sedge[pos] = make_int2(s, __float_as_int(nm));
  }
}

// ---------------- dense layers ----------------
// One wave per node; W column `lane` lives entirely in VGPRs; x row is
// wave-uniform (readfirstlane) so loads scalarize. out[node][lane] coalesced.
template <int K, int COLS>
__global__ __launch_bounds__(256) void k_gemm(const float* __restrict__ x,
                                              const float* __restrict__ W,
                                              float* __restrict__ out, int n) {
  int lane = threadIdx.x & 63;
  int gw = (blockIdx.x * blockDim.x + threadIdx.x) >> 6;
  int nw = (gridDim.x * blockDim.x) >> 6;
  float wreg[K];
#pragma unroll
  for (int k = 0; k < K; ++k) wreg[k] = 0.f;
  if (lane < COLS) {
#pragma unroll
    for (int k = 0; k < K; ++k) wreg[k] = W[k * COLS + lane];
  }
  for (int node = gw; node < n; node += nw) {
    int un = __builtin_amdgcn_readfirstlane(node);
    const float* xr = x + (size_t)un * K;
    float acc = 0.f;
#pragma unroll
    for (int k = 0; k < K; ++k) acc = fmaf(xr[k], wreg[k], acc);
    if (lane < COLS) out[(size_t)un * COLS + lane] = acc;
  }
}

// ---------------- aggregation (CSR gather, no atomics) ----------------
// One wave per node, lane = feature. Edge loop unrolled 8/4/1 so up to 8
// independent gather chains are in flight per wave (latency hiding).
template <int F, bool RELU>
__global__ __launch_bounds__(256) void k_agg(const float* __restrict__ h,
                                             const int* __restrict__ offset,
                                             const int2* __restrict__ sedge,
                                             const float* __restrict__ dinv,
                                             const float* __restrict__ bias,
                                             float* __restrict__ out, int n) {
  int lane = threadIdx.x & 63;
  int node = (blockIdx.x * blockDim.x + threadIdx.x) >> 6;
  if (node >= n) return;
  float di = dinv[node];
  float acc = 0.f;
  if (lane < F) acc = h[(size_t)node * F + lane] * di * di;  // self loop
  int beg = offset[node], end = offset[node + 1];
  int j = beg;
  for (; j + 8 <= end; j += 8) {
    int2 e[8];
#pragma unroll
    for (int u = 0; u < 8; ++u) e[u] = sedge[j + u];
    float v[8];
#pragma unroll
    for (int u = 0; u < 8; ++u)
      v[u] = (lane < F) ? h[(size_t)e[u].x * F + lane] : 0.f;
#pragma unroll
    for (int u = 0; u < 8; ++u) acc = fmaf(v[u], __int_as_float(e[u].y), acc);
  }
  for (; j + 4 <= end; j += 4) {
    int2 e[4];
#pragma unroll
    for (int u = 0; u < 4; ++u) e[u] = sedge[j + u];
    float v[4];
#pragma unroll
    for (int u = 0; u < 4; ++u)
      v[u] = (lane < F) ? h[(size_t)e[u].x * F + lane] : 0.f;
#pragma unroll
    for (int u = 0; u < 4; ++u) acc = fmaf(v[u], __int_as_float(e[u].y), acc);
  }
  for (; j < end; ++j) {
    int2 e = sedge[j];
    if (lane < F) acc = fmaf(h[(size_t)e.x * F + lane], __int_as_float(e.y), acc);
  }
  if (lane < F) {
    float vv = acc + bias[lane];
    if (RELU) vv = fmaxf(vv, 0.f);
    out[(size_t)node * F + lane] = vv;
  }
}

// ---------------- launch ----------------

extern "C" void kernel_launch(void* const* d_in, const int* in_sizes, int n_in,
                              void* d_out, int out_size, void* d_ws, size_t ws_size,
                              hipStream_t stream) {
  const float* x  = (const float*)d_in[0];
  const int*   ei = (const int*)d_in[1];
  const float* W1 = (const float*)d_in[2];
  const float* b1 = (const float*)d_in[3];
  const float* W2 = (const float*)d_in[4];
  const float* b2 = (const float*)d_in[5];
  float* out = (float*)d_out;

  const int F_IN = 128, HID = 64, C = 40;
  int N = in_sizes[0] / F_IN;
  int E = in_sizes[1] / 2;
  const int* src = ei;
  const int* dst = ei + E;

  char* w = (char*)d_ws;
  size_t o = 0;
  auto alloc = [&](size_t bytes) -> void* {
    void* p = w + o;
    o = (o + bytes + 255) & ~(size_t)255;
    return p;
  };
  float* dinv   = (float*)alloc((size_t)N * 4);
  int*   count  = (int*)alloc((size_t)N * 4);
  int*   offset = (int*)alloc((size_t)(N + 1) * 4);
  int*   fill   = (int*)alloc((size_t)N * 4);
  int*   bsum   = (int*)alloc(1024 * 4);
  int2*  sedge  = (int2*)alloc((size_t)E * 8);
  float* h      = (float*)alloc((size_t)N * HID * 4);
  float* h1     = (float*)alloc((size_t)N * HID * 4);
  float* h2     = (float*)alloc((size_t)N * C * 4);

  int nb = (N + 1023) / 1024;  // 98 for N=100000

  dim3 b256(256);
  dim3 gN((N + 255) / 256), gE((E + 255) / 256);

  // degree / CSR build
  k_zero_i32<<<gN, b256, 0, stream>>>(count, N);
  k_count<<<gE, b256, 0, stream>>>(dst, count, E);
  k_dinv<<<gN, b256, 0, stream>>>(count, dinv, N);
  k_scan1<<<dim3(nb), dim3(1024), 0, stream>>>(count, offset, bsum, N);
  k_scan2<<<dim3(1), dim3(1024), 0, stream>>>(bsum, nb);
  k_scan3<<<gN, b256, 0, stream>>>(count, offset, bsum, fill, N, E);
  k_scatter<<<gE, b256, 0, stream>>>(src, dst, dinv, fill, sedge, E);

  // layer 1
  k_gemm<128, 64><<<dim3(768), b256, 0, stream>>>(x, W1, h, N);
  k_agg<64, true><<<dim3((N + 3) / 4), b256, 0, stream>>>(h, offset, sedge, dinv, b1, h1, N);

  // layer 2
  k_gemm<64, 40><<<dim3(768), b256, 0, stream>>>(h1, W2, h2, N);
  k_agg<40, false><<<dim3((N + 3) / 4), b256, 0, stream>>>(h2, offset, sedge, dinv, b2, out, N);
}

// Round 3
// 476.757 us; speedup vs baseline: 1.4584x; 1.0747x over previous
//
#include <hip/hip_runtime.h>
#include <cstdint>
#include <cstddef>

#define NPB_SHIFT 8                      // 256 dst-nodes per bucket
#define NPB (1 << NPB_SHIFT)
#define CHUNK 2048                       // edges per partition block

// ---------------- graph preprocessing ----------------

__global__ void k_zero_i32(int* __restrict__ p, int n) {
  int i = blockIdx.x * blockDim.x + threadIdx.x;
  if (i < n) p[i] = 0;
}

__global__ void k_count(const int* __restrict__ dst, int* __restrict__ count, int E) {
  int e = blockIdx.x * blockDim.x + threadIdx.x;
  if (e < E) atomicAdd(&count[dst[e]], 1);
}

__global__ void k_dinv(const int* __restrict__ count, float* __restrict__ dinv, int n) {
  int i = blockIdx.x * blockDim.x + threadIdx.x;
  if (i < n) dinv[i] = rsqrtf((float)(count[i] + 1));  // +1 self-loop
}

// inclusive scan of 1024-chunks
__global__ void k_scan1(const int* __restrict__ count, int* __restrict__ incl,
                        int* __restrict__ bsum, int n) {
  __shared__ int tmp[1024];
  int tid = threadIdx.x;
  int gid = blockIdx.x * 1024 + tid;
  int v = (gid < n) ? count[gid] : 0;
  tmp[tid] = v;
  __syncthreads();
  for (int off = 1; off < 1024; off <<= 1) {
    int t = (tid >= off) ? tmp[tid - off] : 0;
    __syncthreads();
    tmp[tid] += t;
    __syncthreads();
  }
  if (gid < n) incl[gid] = tmp[tid];
  if (tid == 1023) bsum[blockIdx.x] = tmp[tid];
}

__global__ void k_scan2(int* __restrict__ bsum, int nb) {
  __shared__ int tmp[1024];
  int tid = threadIdx.x;
  int v = (tid < nb) ? bsum[tid] : 0;
  tmp[tid] = v;
  __syncthreads();
  for (int off = 1; off < 1024; off <<= 1) {
    int t = (tid >= off) ? tmp[tid - off] : 0;
    __syncthreads();
    tmp[tid] += t;
    __syncthreads();
  }
  if (tid < nb) bsum[tid] = tmp[tid] - v;  // exclusive
}

__global__ void k_scan3(const int* __restrict__ count, int* __restrict__ offset,
                        const int* __restrict__ bsum, int n, int E) {
  int gid = blockIdx.x * blockDim.x + threadIdx.x;
  if (gid < n) offset[gid] = offset[gid] - count[gid] + bsum[gid >> 10];
  if (gid == 0) offset[n] = E;
}

// bucket fill counters start at each bucket's CSR base
__global__ void k_bfill(const int* __restrict__ offset, int* __restrict__ bfill, int nbuck) {
  int b = blockIdx.x * blockDim.x + threadIdx.x;
  if (b < nbuck) bfill[b] = offset[b << NPB_SHIFT];
}

// pass 1: LDS multisplit into coarse dst-buckets; packed (src<<8)|dst_local, 4B/edge
__global__ __launch_bounds__(256) void k_partition(const int* __restrict__ src,
                                                   const int* __restrict__ dst,
                                                   int* __restrict__ bfill,
                                                   unsigned* __restrict__ tmp,
                                                   int E, int nbuck) {
  __shared__ int cnt[512];
  __shared__ int base[512];
  __shared__ int cur[512];
  int tid = threadIdx.x;
  int cbase = blockIdx.x * CHUNK;
  for (int i = tid; i < nbuck; i += 256) { cnt[i] = 0; cur[i] = 0; }
  __syncthreads();
  int s[8], d[8];
  bool valid[8];
#pragma unroll
  for (int u = 0; u < 8; ++u) {
    int e = cbase + u * 256 + tid;
    valid[u] = e < E;
    s[u] = valid[u] ? src[e] : 0;
    d[u] = valid[u] ? dst[e] : 0;
    if (valid[u]) atomicAdd(&cnt[d[u] >> NPB_SHIFT], 1);
  }
  __syncthreads();
  for (int i = tid; i < nbuck; i += 256)
    if (cnt[i]) base[i] = atomicAdd(&bfill[i], cnt[i]);
  __syncthreads();
#pragma unroll
  for (int u = 0; u < 8; ++u) {
    if (valid[u]) {
      int b = d[u] >> NPB_SHIFT;
      int r = atomicAdd(&cur[b], 1);
      tmp[base[b] + r] = ((unsigned)s[u] << NPB_SHIFT) | (unsigned)(d[u] & (NPB - 1));
    }
  }
}

// pass 2: one block per bucket; LDS fill counters -> exact CSR, writes L2-local
__global__ __launch_bounds__(256) void k_csr(const unsigned* __restrict__ tmp,
                                             const int* __restrict__ offset,
                                             const float* __restrict__ dinv,
                                             int2* __restrict__ sedge, int N) {
  __shared__ int fillL[NPB];
  __shared__ float dloc[NPB];
  int b = blockIdx.x;
  int nbase = b << NPB_SHIFT;
  int nend = min(nbase + NPB, N);
  int nloc = nend - nbase;
  int tid = threadIdx.x;
  for (int i = tid; i < nloc; i += 256) {
    fillL[i] = offset[nbase + i];
    dloc[i] = dinv[nbase + i];
  }
  __syncthreads();
  int ebeg = offset[nbase];
  int eend = offset[nend];
  int j = ebeg + tid;
  // batches of 4 strided loads for MLP
  for (; j + 3 * 256 < eend; j += 4 * 256) {
    unsigned p[4];
#pragma unroll
    for (int u = 0; u < 4; ++u) p[u] = tmp[j + u * 256];
    float dv[4];
#pragma unroll
    for (int u = 0; u < 4; ++u) dv[u] = dinv[p[u] >> NPB_SHIFT];
#pragma unroll
    for (int u = 0; u < 4; ++u) {
      int dl = p[u] & (NPB - 1);
      int pos = atomicAdd(&fillL[dl], 1);
      sedge[pos] = make_int2((int)(p[u] >> NPB_SHIFT), __float_as_int(dv[u] * dloc[dl]));
    }
  }
  for (; j < eend; j += 256) {
    unsigned p = tmp[j];
    int dl = p & (NPB - 1);
    int s = (int)(p >> NPB_SHIFT);
    int pos = atomicAdd(&fillL[dl], 1);
    sedge[pos] = make_int2(s, __float_as_int(dinv[s] * dloc[dl]));
  }
}

// ---------------- dense layers ----------------
template <int K, int COLS>
__global__ __launch_bounds__(256) void k_gemm(const float* __restrict__ x,
                                              const float* __restrict__ W,
                                              float* __restrict__ out, int n) {
  int lane = threadIdx.x & 63;
  int gw = (blockIdx.x * blockDim.x + threadIdx.x) >> 6;
  int nw = (gridDim.x * blockDim.x) >> 6;
  float wreg[K];
#pragma unroll
  for (int k = 0; k < K; ++k) wreg[k] = 0.f;
  if (lane < COLS) {
#pragma unroll
    for (int k = 0; k < K; ++k) wreg[k] = W[k * COLS + lane];
  }
  for (int node = gw; node < n; node += nw) {
    int un = __builtin_amdgcn_readfirstlane(node);
    const float* xr = x + (size_t)un * K;
    float acc = 0.f;
#pragma unroll
    for (int k = 0; k < K; ++k) acc = fmaf(xr[k], wreg[k], acc);
    if (lane < COLS) out[(size_t)un * COLS + lane] = acc;
  }
}

// ---------------- aggregation (CSR gather, no atomics) ----------------
template <int F, bool RELU>
__global__ __launch_bounds__(256) void k_agg(const float* __restrict__ h,
                                             const int* __restrict__ offset,
                                             const int2* __restrict__ sedge,
                                             const float* __restrict__ dinv,
                                             const float* __restrict__ bias,
                                             float* __restrict__ out, int n) {
  int lane = threadIdx.x & 63;
  int node = (blockIdx.x * blockDim.x + threadIdx.x) >> 6;
  if (node >= n) return;
  float di = dinv[node];
  float acc = 0.f;
  if (lane < F) acc = h[(size_t)node * F + lane] * di * di;  // self loop
  int beg = offset[node], end = offset[node + 1];
  int j = beg;
  for (; j + 8 <= end; j += 8) {
    int2 e[8];
#pragma unroll
    for (int u = 0; u < 8; ++u) e[u] = sedge[j + u];
    float v[8];
#pragma unroll
    for (int u = 0; u < 8; ++u)
      v[u] = (lane < F) ? h[(size_t)e[u].x * F + lane] : 0.f;
#pragma unroll
    for (int u = 0; u < 8; ++u) acc = fmaf(v[u], __int_as_float(e[u].y), acc);
  }
  for (; j + 4 <= end; j += 4) {
    int2 e[4];
#pragma unroll
    for (int u = 0; u < 4; ++u) e[u] = sedge[j + u];
    float v[4];
#pragma unroll
    for (int u = 0; u < 4; ++u)
      v[u] = (lane < F) ? h[(size_t)e[u].x * F + lane] : 0.f;
#pragma unroll
    for (int u = 0; u < 4; ++u) acc = fmaf(v[u], __int_as_float(e[u].y), acc);
  }
  for (; j < end; ++j) {
    int2 e = sedge[j];
    if (lane < F) acc = fmaf(h[(size_t)e.x * F + lane], __int_as_float(e.y), acc);
  }
  if (lane < F) {
    float vv = acc + bias[lane];
    if (RELU) vv = fmaxf(vv, 0.f);
    out[(size_t)node * F + lane] = vv;
  }
}

// ---------------- launch ----------------

extern "C" void kernel_launch(void* const* d_in, const int* in_sizes, int n_in,
                              void* d_out, int out_size, void* d_ws, size_t ws_size,
                              hipStream_t stream) {
  const float* x  = (const float*)d_in[0];
  const int*   ei = (const int*)d_in[1];
  const float* W1 = (const float*)d_in[2];
  const float* b1 = (const float*)d_in[3];
  const float* W2 = (const float*)d_in[4];
  const float* b2 = (const float*)d_in[5];
  float* out = (float*)d_out;

  const int F_IN = 128, HID = 64, C = 40;
  int N = in_sizes[0] / F_IN;
  int E = in_sizes[1] / 2;
  const int* src = ei;
  const int* dst = ei + E;
  int nbuck = (N + NPB - 1) >> NPB_SHIFT;   // 391 for N=100000

  char* w = (char*)d_ws;
  size_t o = 0;
  auto alloc = [&](size_t bytes) -> void* {
    void* p = w + o;
    o = (o + bytes + 255) & ~(size_t)255;
    return p;
  };
  float*    dinv   = (float*)alloc((size_t)N * 4);
  int*      count  = (int*)alloc((size_t)N * 4);
  int*      offset = (int*)alloc((size_t)(N + 1) * 4);
  int*      bsum   = (int*)alloc(1024 * 4);
  int*      bfill  = (int*)alloc((size_t)nbuck * 4);
  unsigned* tmp    = (unsigned*)alloc((size_t)E * 4);
  int2*     sedge  = (int2*)alloc((size_t)E * 8);
  float*    h      = (float*)alloc((size_t)N * HID * 4);
  float*    h1     = (float*)alloc((size_t)N * HID * 4);
  float*    h2     = (float*)alloc((size_t)N * C * 4);

  int nb = (N + 1023) / 1024;

  dim3 b256(256);
  dim3 gN((N + 255) / 256), gE((E + 255) / 256);

  // degree / offsets
  k_zero_i32<<<gN, b256, 0, stream>>>(count, N);
  k_count<<<gE, b256, 0, stream>>>(dst, count, E);
  k_dinv<<<gN, b256, 0, stream>>>(count, dinv, N);
  k_scan1<<<dim3(nb), dim3(1024), 0, stream>>>(count, offset, bsum, N);
  k_scan2<<<dim3(1), dim3(1024), 0, stream>>>(bsum, nb);
  k_scan3<<<gN, b256, 0, stream>>>(count, offset, bsum, N, E);

  // locality-aware CSR build
  k_bfill<<<dim3((nbuck + 255) / 256), b256, 0, stream>>>(offset, bfill, nbuck);
  k_partition<<<dim3((E + CHUNK - 1) / CHUNK), b256, 0, stream>>>(src, dst, bfill, tmp, E, nbuck);
  k_csr<<<dim3(nbuck), b256, 0, stream>>>(tmp, offset, dinv, sedge, N);

  // layer 1
  k_gemm<128, 64><<<dim3(768), b256, 0, stream>>>(x, W1, h, N);
  k_agg<64, true><<<dim3((N + 3) / 4), b256, 0, stream>>>(h, offset, sedge, dinv, b1, h1, N);

  // layer 2
  k_gemm<64, 40><<<dim3(768), b256, 0, stream>>>(h1, W2, h2, N);
  k_agg<40, false><<<dim3((N + 3) / 4), b256, 0, stream>>>(h2, offset, sedge, dinv, b2, out, N);
}